// Round 1
// baseline (271.664 us; speedup 1.0000x reference)
//
#include <hip/hip_runtime.h>

#define NB 4            // batches
#define NA 120000       // anchors
#define NC 80           // classes
#define NM 32           // annotations per batch

#define ALPHA_ 0.75f
#define EPS_   1e-4f

constexpr int BLOCK = 256;
constexpr int APB   = 256;          // anchors per block
constexpr int F4_PER_ANCHOR = NC / 4;   // 20

__device__ __forceinline__ float wave_reduce(float v) {
    #pragma unroll
    for (int off = 32; off > 0; off >>= 1) v += __shfl_down(v, off, 64);
    return v;
}

__device__ __forceinline__ float focal_term(float x, int meta, int c) {
    // meta: >=0 pos assigned class, -1 neg (targets all 0). (ignore never reaches here)
    float p = fminf(fmaxf(x, EPS_), 1.0f - EPS_);
    if (meta == c) {
        float q = 1.0f - p;
        return ALPHA_ * q * q * (-logf(p));
    } else {
        return (1.0f - ALPHA_) * p * p * (-logf(1.0f - p));
    }
}

__global__ __launch_bounds__(BLOCK)
void focal_main(const float* __restrict__ cls,
                const float* __restrict__ reg,
                const float* __restrict__ anchors,
                const float* __restrict__ ann,
                double* __restrict__ acc)   // [NB][3]: cls_sum, reg_sum, pos_cnt
{
    __shared__ float s_ann[NM * 10];
    __shared__ int   s_meta[APB];      // -2 ignore/out-of-range, -1 neg, >=0 pos class
    __shared__ float s_red[3][4];

    const int b   = blockIdx.y;
    const int a0  = blockIdx.x * APB;
    const int tid = threadIdx.x;

    for (int i = tid; i < NM * 10; i += BLOCK)
        s_ann[i] = ann[b * NM * 10 + i];
    __syncthreads();

    float regLoss = 0.0f;
    float posCnt  = 0.0f;
    const int a = a0 + tid;

    if (a < NA) {
        const float4 an = ((const float4*)anchors)[a];
        const float ax1 = an.x, ay1 = an.y, ax2 = an.z, ay2 = an.w;
        const float aw  = ax2 - ax1, ah = ay2 - ay1;
        const float acx = ax1 + 0.5f * aw, acy = ay1 + 0.5f * ah;
        const float areaA = aw * ah;

        float best = -1.0f;
        int   arg  = 0;
        #pragma unroll
        for (int m = 0; m < NM; ++m) {
            const float bx1 = s_ann[m * 10 + 4];
            const float by1 = s_ann[m * 10 + 5];
            const float bx2 = s_ann[m * 10 + 6];
            const float by2 = s_ann[m * 10 + 7];
            float iw = fminf(ax2, bx2) - fmaxf(ax1, bx1); iw = fmaxf(iw, 0.0f);
            float ih = fminf(ay2, by2) - fmaxf(ay1, by1); ih = fmaxf(ih, 0.0f);
            const float inter = iw * ih;
            const float areaB = (bx2 - bx1) * (by2 - by1);
            const float ua    = fmaxf(areaA + areaB - inter, 1e-8f);
            const float iou   = inter / ua;
            if (iou > best) { best = iou; arg = m; }   // first-max (jnp.argmax)
        }

        int meta;
        if (best >= 0.5f) {
            meta   = (int)s_ann[arg * 10 + 8];
            posCnt = 1.0f;
            // regression loss: only components 0..3 (full box) survive the mask
            const float fx1 = s_ann[arg * 10 + 4];
            const float fy1 = s_ann[arg * 10 + 5];
            const float fx2 = s_ann[arg * 10 + 6];
            const float fy2 = s_ann[arg * 10 + 7];
            float gw = fx2 - fx1, gh = fy2 - fy1;
            const float gcx = fx1 + 0.5f * gw, gcy = fy1 + 0.5f * gh; // pre-clip centers
            gw = fmaxf(gw, 1.0f); gh = fmaxf(gh, 1.0f);
            const float t0 = ((gcx - acx) / aw) / 0.1f;
            const float t1 = ((gcy - acy) / ah) / 0.1f;
            const float t2 = logf(gw / aw) / 0.2f;
            const float t3 = logf(gh / ah) / 0.2f;
            const float4 r4 = ((const float4*)reg)[(size_t)(b * NA + a) * 2];
            const float d0 = fabsf(t0 - r4.x);
            const float d1 = fabsf(t1 - r4.y);
            const float d2 = fabsf(t2 - r4.z);
            const float d3 = fabsf(t3 - r4.w);
            const float beta = 1.0f / 9.0f;
            #define SL1(d) ((d) <= beta ? 4.5f * (d) * (d) : (d) - 0.5f / 9.0f)
            regLoss = SL1(d0) + SL1(d1) + SL1(d2) + SL1(d3);
            #undef SL1
        } else if (best < 0.4f) {
            meta = -1;
        } else {
            meta = -2;   // ignore: zero cls loss, skip loads
        }
        s_meta[tid] = meta;
    } else {
        s_meta[tid] = -2;
    }
    __syncthreads();

    // Phase 2: coalesced focal-loss sweep over this block's 256 anchors x 80 classes.
    float clsSum = 0.0f;
    const float4* cls4 = (const float4*)(cls + (size_t)b * NA * NC);
    #pragma unroll
    for (int it = 0; it < APB * F4_PER_ANCHOR / BLOCK; ++it) {   // 20 iters
        const int idx = it * BLOCK + tid;          // 0..5119, consecutive -> coalesced
        const int la  = idx / F4_PER_ANCHOR;
        const int c4  = idx % F4_PER_ANCHOR;
        const int ga  = a0 + la;
        const int meta = s_meta[la];
        if (meta != -2 && ga < NA) {
            const float4 p4 = cls4[(size_t)ga * F4_PER_ANCHOR + c4];
            const int cb = c4 * 4;
            clsSum += focal_term(p4.x, meta, cb + 0);
            clsSum += focal_term(p4.y, meta, cb + 1);
            clsSum += focal_term(p4.z, meta, cb + 2);
            clsSum += focal_term(p4.w, meta, cb + 3);
        }
    }

    // Block reduce (wave shuffle -> LDS -> one double atomic per quantity)
    const int wave = tid >> 6, lane = tid & 63;
    float rc = wave_reduce(clsSum);
    float rr = wave_reduce(regLoss);
    float rp = wave_reduce(posCnt);
    if (lane == 0) { s_red[0][wave] = rc; s_red[1][wave] = rr; s_red[2][wave] = rp; }
    __syncthreads();
    if (tid == 0) {
        float c = s_red[0][0] + s_red[0][1] + s_red[0][2] + s_red[0][3];
        float r = s_red[1][0] + s_red[1][1] + s_red[1][2] + s_red[1][3];
        float p = s_red[2][0] + s_red[2][1] + s_red[2][2] + s_red[2][3];
        atomicAdd(&acc[b * 3 + 0], (double)c);
        atomicAdd(&acc[b * 3 + 1], (double)r);
        atomicAdd(&acc[b * 3 + 2], (double)p);
    }
}

__global__ void focal_finalize(const double* __restrict__ acc, float* __restrict__ out) {
    double clsTot = 0.0, regTot = 0.0;
    #pragma unroll
    for (int b = 0; b < NB; ++b) {
        const double np  = acc[b * 3 + 2];
        const double npc = np < 1.0 ? 1.0 : np;
        clsTot += acc[b * 3 + 0] / npc;
        regTot += (np > 0.0) ? acc[b * 3 + 1] / (npc * 4.0) : 0.0;
    }
    out[0] = (float)(clsTot / NB);
    out[1] = (float)(regTot / NB);
}

extern "C" void kernel_launch(void* const* d_in, const int* in_sizes, int n_in,
                              void* d_out, int out_size, void* d_ws, size_t ws_size,
                              hipStream_t stream) {
    const float* cls     = (const float*)d_in[0];   // (B, A, C)
    const float* reg     = (const float*)d_in[1];   // (B, A, 8)
    const float* anchors = (const float*)d_in[2];   // (1, A, 4)
    const float* ann     = (const float*)d_in[3];   // (B, M, 10)
    float* out = (float*)d_out;
    double* acc = (double*)d_ws;                    // NB*3 doubles

    hipMemsetAsync(acc, 0, NB * 3 * sizeof(double), stream);

    dim3 grid((NA + APB - 1) / APB, NB);
    focal_main<<<grid, BLOCK, 0, stream>>>(cls, reg, anchors, ann, acc);
    focal_finalize<<<1, 1, 0, stream>>>(acc, out);
}

// Round 2
// 264.191 us; speedup vs baseline: 1.0283x; 1.0283x over previous
//
#include <hip/hip_runtime.h>

#define NB 4            // batches
#define NA 120000       // anchors
#define NC 80           // classes
#define NM 32           // annotations per batch

#define ALPHA_ 0.75f
#define EPS_   1e-4f
#define LN2_   0.69314718055994531f

constexpr int BLOCK = 192;                 // 3 waves
constexpr int APB   = 192;                 // anchors per block; 120000 = 625 * 192 exactly
constexpr int F4_PER_ANCHOR = NC / 4;      // 20
constexpr int P2_ITERS = APB * F4_PER_ANCHOR / BLOCK;  // 20

__device__ __forceinline__ float wave_reduce(float v) {
    #pragma unroll
    for (int off = 32; off > 0; off >>= 1) v += __shfl_down(v, off, 64);
    return v;
}

// fast log2 -> v_log_f32 (inputs are clamped well away from denormals)
__device__ __forceinline__ float flog2(float x) { return __builtin_amdgcn_logf(x); }

__global__ __launch_bounds__(BLOCK)
void focal_main(const float* __restrict__ cls,
                const float* __restrict__ reg,
                const float* __restrict__ anchors,
                const float* __restrict__ ann,
                double* __restrict__ acc)   // [NB][3]: cls_sum, reg_sum, pos_cnt
{
    __shared__ float s_ann[NM * 10];
    __shared__ float s_coef[APB];        // per-anchor coefficient for neg-term sweep
    __shared__ float s_red[3][3];

    const int b   = blockIdx.y;
    const int a0  = blockIdx.x * APB;
    const int tid = threadIdx.x;

    for (int i = tid; i < NM * 10; i += BLOCK)
        s_ann[i] = ann[b * NM * 10 + i];
    __syncthreads();

    // ---------------- Phase 1: per-anchor metadata (one anchor per thread) ---------
    float regLoss = 0.0f;
    float posCnt  = 0.0f;
    float clsCorr = 0.0f;                 // positive-class correction term
    const int a = a0 + tid;               // always < NA (exact division)

    {
        const float4 an = ((const float4*)anchors)[a];
        const float ax1 = an.x, ay1 = an.y, ax2 = an.z, ay2 = an.w;
        const float aw  = ax2 - ax1, ah = ay2 - ay1;
        const float acx = ax1 + 0.5f * aw, acy = ay1 + 0.5f * ah;
        const float areaA = aw * ah;

        float best = -1.0f;
        int   arg  = 0;
        #pragma unroll
        for (int m = 0; m < NM; ++m) {
            const float bx1 = s_ann[m * 10 + 4];
            const float by1 = s_ann[m * 10 + 5];
            const float bx2 = s_ann[m * 10 + 6];
            const float by2 = s_ann[m * 10 + 7];
            float iw = fminf(ax2, bx2) - fmaxf(ax1, bx1); iw = fmaxf(iw, 0.0f);
            float ih = fminf(ay2, by2) - fmaxf(ay1, by1); ih = fmaxf(ih, 0.0f);
            const float inter = iw * ih;
            const float areaB = (bx2 - bx1) * (by2 - by1);
            const float ua    = fmaxf(areaA + areaB - inter, 1e-8f);
            const float iou   = inter / ua;
            if (iou > best) { best = iou; arg = m; }   // first-max (jnp.argmax)
        }

        // coefficient for the uniform negative-term sweep:
        //   non-ignore: sum += p^2 * log2(1-p) * (-0.25*ln2)
        //   ignore (0.4 <= iou < 0.5): 0
        const bool pos = best >= 0.5f;
        const bool neg = best < 0.4f;
        s_coef[tid] = (pos || neg) ? (-0.25f * LN2_) : 0.0f;

        if (pos) {
            posCnt = 1.0f;
            const int c = (int)s_ann[arg * 10 + 8];
            // correction: replace neg-term with pos-term at the assigned class
            const float x  = cls[((size_t)b * NA + a) * NC + c];
            const float p  = fminf(fmaxf(x, EPS_), 1.0f - EPS_);
            const float q  = 1.0f - p;
            const float posT = 0.75f * q * q * (-LN2_ * flog2(p));
            const float negT = 0.25f * p * p * (-LN2_ * flog2(q));
            clsCorr = posT - negT;

            // regression loss: only components 0..3 (full box) survive the mask
            const float fx1 = s_ann[arg * 10 + 4];
            const float fy1 = s_ann[arg * 10 + 5];
            const float fx2 = s_ann[arg * 10 + 6];
            const float fy2 = s_ann[arg * 10 + 7];
            float gw = fx2 - fx1, gh = fy2 - fy1;
            const float gcx = fx1 + 0.5f * gw, gcy = fy1 + 0.5f * gh; // pre-clip centers
            gw = fmaxf(gw, 1.0f); gh = fmaxf(gh, 1.0f);
            const float t0 = ((gcx - acx) / aw) * 10.0f;
            const float t1 = ((gcy - acy) / ah) * 10.0f;
            const float t2 = (LN2_ * flog2(gw / aw)) * 5.0f;
            const float t3 = (LN2_ * flog2(gh / ah)) * 5.0f;
            const float4 r4 = ((const float4*)reg)[(size_t)(b * NA + a) * 2];
            const float d0 = fabsf(t0 - r4.x);
            const float d1 = fabsf(t1 - r4.y);
            const float d2 = fabsf(t2 - r4.z);
            const float d3 = fabsf(t3 - r4.w);
            const float beta = 1.0f / 9.0f;
            #define SL1(d) ((d) <= beta ? 4.5f * (d) * (d) : (d) - 0.5f / 9.0f)
            regLoss = SL1(d0) + SL1(d1) + SL1(d2) + SL1(d3);
            #undef SL1
        }
    }
    __syncthreads();

    // ---------------- Phase 2: branch-free coalesced neg-term sweep ----------------
    // sum over all 80 classes of all APB anchors:  p^2 * log2(1-p) * coef[anchor]
    float clsSum = clsCorr;
    const float4* cls4 = (const float4*)(cls + (size_t)b * NA * NC) + (size_t)a0 * F4_PER_ANCHOR;
    #pragma unroll
    for (int it = 0; it < P2_ITERS; ++it) {
        const int idx = it * BLOCK + tid;          // 0..3839, consecutive -> coalesced
        const int la  = idx / F4_PER_ANCHOR;       // anchor within block (magic-mul)
        const float C = s_coef[la];
        const float4 x4 = cls4[idx];

        float p0 = fminf(fmaxf(x4.x, EPS_), 1.0f - EPS_);
        float p1 = fminf(fmaxf(x4.y, EPS_), 1.0f - EPS_);
        float p2 = fminf(fmaxf(x4.z, EPS_), 1.0f - EPS_);
        float p3 = fminf(fmaxf(x4.w, EPS_), 1.0f - EPS_);

        float t0 = p0 * p0 * flog2(1.0f - p0);
        float t1 = p1 * p1 * flog2(1.0f - p1);
        float t2 = p2 * p2 * flog2(1.0f - p2);
        float t3 = p3 * p3 * flog2(1.0f - p3);

        clsSum = fmaf((t0 + t1) + (t2 + t3), C, clsSum);
    }

    // ---------------- Block reduce -> one double atomic per quantity ---------------
    const int wave = tid >> 6, lane = tid & 63;
    float rc = wave_reduce(clsSum);
    float rr = wave_reduce(regLoss);
    float rp = wave_reduce(posCnt);
    if (lane == 0) { s_red[0][wave] = rc; s_red[1][wave] = rr; s_red[2][wave] = rp; }
    __syncthreads();
    if (tid == 0) {
        float c = s_red[0][0] + s_red[0][1] + s_red[0][2];
        float r = s_red[1][0] + s_red[1][1] + s_red[1][2];
        float p = s_red[2][0] + s_red[2][1] + s_red[2][2];
        atomicAdd(&acc[b * 3 + 0], (double)c);
        atomicAdd(&acc[b * 3 + 1], (double)r);
        atomicAdd(&acc[b * 3 + 2], (double)p);
    }
}

__global__ void focal_finalize(const double* __restrict__ acc, float* __restrict__ out) {
    double clsTot = 0.0, regTot = 0.0;
    #pragma unroll
    for (int b = 0; b < NB; ++b) {
        const double np  = acc[b * 3 + 2];
        const double npc = np < 1.0 ? 1.0 : np;
        clsTot += acc[b * 3 + 0] / npc;
        regTot += (np > 0.0) ? acc[b * 3 + 1] / (npc * 4.0) : 0.0;
    }
    out[0] = (float)(clsTot / NB);
    out[1] = (float)(regTot / NB);
}

extern "C" void kernel_launch(void* const* d_in, const int* in_sizes, int n_in,
                              void* d_out, int out_size, void* d_ws, size_t ws_size,
                              hipStream_t stream) {
    const float* cls     = (const float*)d_in[0];   // (B, A, C)
    const float* reg     = (const float*)d_in[1];   // (B, A, 8)
    const float* anchors = (const float*)d_in[2];   // (1, A, 4)
    const float* ann     = (const float*)d_in[3];   // (B, M, 10)
    float* out = (float*)d_out;
    double* acc = (double*)d_ws;                    // NB*3 doubles

    hipMemsetAsync(acc, 0, NB * 3 * sizeof(double), stream);

    dim3 grid(NA / APB, NB);                        // 625 x 4, exact
    focal_main<<<grid, BLOCK, 0, stream>>>(cls, reg, anchors, ann, acc);
    focal_finalize<<<1, 1, 0, stream>>>(acc, out);
}

// Round 3
// 258.967 us; speedup vs baseline: 1.0490x; 1.0202x over previous
//
#include <hip/hip_runtime.h>

#define NB 4            // batches
#define NA 120000       // anchors
#define NC 80           // classes
#define NM 32           // annotations per batch

#define ALPHA_ 0.75f
#define EPS_   1e-4f
#define LN2_   0.69314718055994531f

constexpr int BLOCK = 192;                 // 3 waves
constexpr int APB   = 192;                 // anchors per block; 120000 = 625 * 192 exactly
constexpr int F4_PER_ANCHOR = NC / 4;      // 20
constexpr int P2_ITERS = APB * F4_PER_ANCHOR / BLOCK;  // 20

__device__ __forceinline__ float wave_reduce(float v) {
    #pragma unroll
    for (int off = 32; off > 0; off >>= 1) v += __shfl_down(v, off, 64);
    return v;
}

// fast log2 -> v_log_f32 (inputs are clamped well away from denormals)
__device__ __forceinline__ float flog2(float x) { return __builtin_amdgcn_logf(x); }

__global__ __launch_bounds__(BLOCK)
void focal_main(const float* __restrict__ cls,
                const float* __restrict__ reg,
                const float* __restrict__ anchors,
                const float* __restrict__ ann,
                double* __restrict__ acc)   // [NB][3]: cls_sum, reg_sum, pos_cnt
{
    __shared__ float s_ann[NM * 10];
    __shared__ float s_coef[APB];        // per-anchor coefficient for neg-term sweep
    __shared__ float s_red[3][3];

    const int b   = blockIdx.y;
    const int a0  = blockIdx.x * APB;
    const int tid = threadIdx.x;

    // ---- Issue phase: get every global load in flight before any compute ----
    // 1) anchor box (needed first in phase 1)
    const float4 an = ((const float4*)anchors)[a0 + tid];

    // 2) annotation staging loads (needed at phase-1 start, after ds_write+barrier)
    const float* annB = ann + b * NM * 10;
    const float av0 = annB[tid];
    const float av1 = (tid < NM * 10 - BLOCK) ? annB[BLOCK + tid] : 0.0f;

    // 3) all 20 classification float4 loads -> register array (the MLP payload).
    //    Addresses are independent of phase 1, so these stay in flight across
    //    the barrier and phase-1 compute (~1000 cy) hides their latency.
    const float4* cls4 = (const float4*)(cls + (size_t)b * NA * NC) + (size_t)a0 * F4_PER_ANCHOR;
    float4 x[P2_ITERS];
    #pragma unroll
    for (int it = 0; it < P2_ITERS; ++it)
        x[it] = cls4[it * BLOCK + tid];

    // ds_write waits only on the ann loads (issued before the x loads)
    s_ann[tid] = av0;
    if (tid < NM * 10 - BLOCK) s_ann[BLOCK + tid] = av1;
    __syncthreads();

    // ---------------- Phase 1: per-anchor metadata (one anchor per thread) ---------
    float regLoss = 0.0f;
    float posCnt  = 0.0f;
    float clsCorr = 0.0f;                 // positive-class correction term
    const int a = a0 + tid;               // always < NA (exact division)

    {
        const float ax1 = an.x, ay1 = an.y, ax2 = an.z, ay2 = an.w;
        const float aw  = ax2 - ax1, ah = ay2 - ay1;
        const float acx = ax1 + 0.5f * aw, acy = ay1 + 0.5f * ah;
        const float areaA = aw * ah;

        float best = -1.0f;
        int   arg  = 0;
        #pragma unroll
        for (int m = 0; m < NM; ++m) {
            const float bx1 = s_ann[m * 10 + 4];
            const float by1 = s_ann[m * 10 + 5];
            const float bx2 = s_ann[m * 10 + 6];
            const float by2 = s_ann[m * 10 + 7];
            float iw = fminf(ax2, bx2) - fmaxf(ax1, bx1); iw = fmaxf(iw, 0.0f);
            float ih = fminf(ay2, by2) - fmaxf(ay1, by1); ih = fmaxf(ih, 0.0f);
            const float inter = iw * ih;
            const float areaB = (bx2 - bx1) * (by2 - by1);
            const float ua    = fmaxf(areaA + areaB - inter, 1e-8f);
            const float iou   = inter / ua;
            if (iou > best) { best = iou; arg = m; }   // first-max (jnp.argmax)
        }

        // coefficient for the uniform negative-term sweep:
        //   non-ignore: sum += p^2 * log2(1-p) * (-0.25*ln2)
        //   ignore (0.4 <= iou < 0.5): 0
        const bool pos = best >= 0.5f;
        const bool neg = best < 0.4f;
        s_coef[tid] = (pos || neg) ? (-0.25f * LN2_) : 0.0f;

        if (pos) {
            posCnt = 1.0f;
            const int c = (int)s_ann[arg * 10 + 8];
            // correction: replace neg-term with pos-term at the assigned class
            const float xc = cls[((size_t)b * NA + a) * NC + c];
            const float p  = fminf(fmaxf(xc, EPS_), 1.0f - EPS_);
            const float q  = 1.0f - p;
            const float posT = 0.75f * q * q * (-LN2_ * flog2(p));
            const float negT = 0.25f * p * p * (-LN2_ * flog2(q));
            clsCorr = posT - negT;

            // regression loss: only components 0..3 (full box) survive the mask
            const float fx1 = s_ann[arg * 10 + 4];
            const float fy1 = s_ann[arg * 10 + 5];
            const float fx2 = s_ann[arg * 10 + 6];
            const float fy2 = s_ann[arg * 10 + 7];
            float gw = fx2 - fx1, gh = fy2 - fy1;
            const float gcx = fx1 + 0.5f * gw, gcy = fy1 + 0.5f * gh; // pre-clip centers
            gw = fmaxf(gw, 1.0f); gh = fmaxf(gh, 1.0f);
            const float t0 = ((gcx - acx) / aw) * 10.0f;
            const float t1 = ((gcy - acy) / ah) * 10.0f;
            const float t2 = (LN2_ * flog2(gw / aw)) * 5.0f;
            const float t3 = (LN2_ * flog2(gh / ah)) * 5.0f;
            const float4 r4 = ((const float4*)reg)[(size_t)(b * NA + a) * 2];
            const float d0 = fabsf(t0 - r4.x);
            const float d1 = fabsf(t1 - r4.y);
            const float d2 = fabsf(t2 - r4.z);
            const float d3 = fabsf(t3 - r4.w);
            const float beta = 1.0f / 9.0f;
            #define SL1(d) ((d) <= beta ? 4.5f * (d) * (d) : (d) - 0.5f / 9.0f)
            regLoss = SL1(d0) + SL1(d1) + SL1(d2) + SL1(d3);
            #undef SL1
        }
    }
    __syncthreads();

    // ---------------- Phase 2: branch-free sweep over preloaded registers ----------
    // sum over all 80 classes of all APB anchors:  p^2 * log2(1-p) * coef[anchor]
    float clsSum = clsCorr;
    #pragma unroll
    for (int it = 0; it < P2_ITERS; ++it) {
        const int idx = it * BLOCK + tid;
        const float C = s_coef[idx / F4_PER_ANCHOR];
        const float4 x4 = x[it];

        float p0 = fminf(fmaxf(x4.x, EPS_), 1.0f - EPS_);
        float p1 = fminf(fmaxf(x4.y, EPS_), 1.0f - EPS_);
        float p2 = fminf(fmaxf(x4.z, EPS_), 1.0f - EPS_);
        float p3 = fminf(fmaxf(x4.w, EPS_), 1.0f - EPS_);

        float t0 = p0 * p0 * flog2(1.0f - p0);
        float t1 = p1 * p1 * flog2(1.0f - p1);
        float t2 = p2 * p2 * flog2(1.0f - p2);
        float t3 = p3 * p3 * flog2(1.0f - p3);

        clsSum = fmaf((t0 + t1) + (t2 + t3), C, clsSum);
    }

    // ---------------- Block reduce -> one double atomic per quantity ---------------
    const int wave = tid >> 6, lane = tid & 63;
    float rc = wave_reduce(clsSum);
    float rr = wave_reduce(regLoss);
    float rp = wave_reduce(posCnt);
    if (lane == 0) { s_red[0][wave] = rc; s_red[1][wave] = rr; s_red[2][wave] = rp; }
    __syncthreads();
    if (tid == 0) {
        float c = s_red[0][0] + s_red[0][1] + s_red[0][2];
        float r = s_red[1][0] + s_red[1][1] + s_red[1][2];
        float p = s_red[2][0] + s_red[2][1] + s_red[2][2];
        atomicAdd(&acc[b * 3 + 0], (double)c);
        atomicAdd(&acc[b * 3 + 1], (double)r);
        atomicAdd(&acc[b * 3 + 2], (double)p);
    }
}

__global__ void focal_finalize(const double* __restrict__ acc, float* __restrict__ out) {
    double clsTot = 0.0, regTot = 0.0;
    #pragma unroll
    for (int b = 0; b < NB; ++b) {
        const double np  = acc[b * 3 + 2];
        const double npc = np < 1.0 ? 1.0 : np;
        clsTot += acc[b * 3 + 0] / npc;
        regTot += (np > 0.0) ? acc[b * 3 + 1] / (npc * 4.0) : 0.0;
    }
    out[0] = (float)(clsTot / NB);
    out[1] = (float)(regTot / NB);
}

extern "C" void kernel_launch(void* const* d_in, const int* in_sizes, int n_in,
                              void* d_out, int out_size, void* d_ws, size_t ws_size,
                              hipStream_t stream) {
    const float* cls     = (const float*)d_in[0];   // (B, A, C)
    const float* reg     = (const float*)d_in[1];   // (B, A, 8)
    const float* anchors = (const float*)d_in[2];   // (1, A, 4)
    const float* ann     = (const float*)d_in[3];   // (B, M, 10)
    float* out = (float*)d_out;
    double* acc = (double*)d_ws;                    // NB*3 doubles

    hipMemsetAsync(acc, 0, NB * 3 * sizeof(double), stream);

    dim3 grid(NA / APB, NB);                        // 625 x 4, exact
    focal_main<<<grid, BLOCK, 0, stream>>>(cls, reg, anchors, ann, acc);
    focal_finalize<<<1, 1, 0, stream>>>(acc, out);
}

// Round 4
// 235.918 us; speedup vs baseline: 1.1515x; 1.0977x over previous
//
#include <hip/hip_runtime.h>

#define NB 4            // batches
#define NA 120000       // anchors
#define NC 80           // classes
#define NM 32           // annotations per batch

#define EPS_   1e-4f
#define LN2_   0.69314718055994531f

constexpr int BLOCK = 256;                 // 4 waves
constexpr int APB   = 64;                  // anchors per block; 120000 = 1875 * 64 exactly
constexpr int U     = 5;                   // float4 per thread; 256*5 = 1280 = 64 anchors * 20
constexpr int BINS  = 64;                  // atomic spreading bins per (batch, quantity)
// acc layout: [(b*3+q)*BINS + bin], q: 0=cls_sum, 1=reg_sum, 2=pos_cnt  (768 doubles)

__device__ __forceinline__ float wave_reduce_f(float v) {
    #pragma unroll
    for (int off = 32; off > 0; off >>= 1) v += __shfl_down(v, off, 64);
    return v;
}
__device__ __forceinline__ double wave_reduce_d(double v) {
    #pragma unroll
    for (int off = 32; off > 0; off >>= 1) v += __shfl_down(v, off, 64);
    return v;
}

// fast log2 -> v_log_f32 (inputs are clamped well away from denormals)
__device__ __forceinline__ float flog2(float x) { return __builtin_amdgcn_logf(x); }

__global__ __launch_bounds__(BLOCK)
void focal_fused(const float* __restrict__ cls,
                 const float* __restrict__ reg,
                 const float* __restrict__ anchors,
                 const float* __restrict__ ann,
                 double* __restrict__ acc)
{
    __shared__ float s_ann[NM * 10];
    __shared__ float s_coef[APB];
    __shared__ float s_red[4];
    __shared__ float s_rp[2];

    const int b   = blockIdx.y;
    const int a0  = blockIdx.x * APB;
    const int tid = threadIdx.x;

    // stage annotations (320 floats)
    const float* annB = ann + b * NM * 10;
    if (tid < NM * 10 - BLOCK) s_ann[BLOCK + tid] = annB[BLOCK + tid];
    s_ann[tid] = annB[tid];
    __syncthreads();

    // ---------------- Phase 1: wave 0 computes meta for the block's 64 anchors ----
    float regLoss = 0.0f;
    float posCnt  = 0.0f;
    float clsCorr = 0.0f;                 // positive-class correction term

    if (tid < APB) {
        const int a = a0 + tid;
        const float4 an = ((const float4*)anchors)[a];
        const float ax1 = an.x, ay1 = an.y, ax2 = an.z, ay2 = an.w;
        const float aw  = ax2 - ax1, ah = ay2 - ay1;
        const float acx = ax1 + 0.5f * aw, acy = ay1 + 0.5f * ah;
        const float areaA = aw * ah;

        float best = -1.0f;
        int   arg  = 0;
        #pragma unroll
        for (int m = 0; m < NM; ++m) {
            const float bx1 = s_ann[m * 10 + 4];
            const float by1 = s_ann[m * 10 + 5];
            const float bx2 = s_ann[m * 10 + 6];
            const float by2 = s_ann[m * 10 + 7];
            float iw = fminf(ax2, bx2) - fmaxf(ax1, bx1); iw = fmaxf(iw, 0.0f);
            float ih = fminf(ay2, by2) - fmaxf(ay1, by1); ih = fmaxf(ih, 0.0f);
            const float inter = iw * ih;
            const float areaB = (bx2 - bx1) * (by2 - by1);
            const float ua    = fmaxf(areaA + areaB - inter, 1e-8f);
            const float iou   = inter / ua;
            if (iou > best) { best = iou; arg = m; }   // first-max (jnp.argmax)
        }

        const bool pos = best >= 0.5f;
        const bool neg = best < 0.4f;
        // non-ignore anchors get coef -0.25*ln2 for the uniform neg-term sweep
        s_coef[tid] = (pos || neg) ? (-0.25f * LN2_) : 0.0f;

        if (pos) {
            posCnt = 1.0f;
            const int c = (int)s_ann[arg * 10 + 8];
            // correction: replace neg-term with pos-term at the assigned class
            const float xc = cls[((size_t)b * NA + a) * NC + c];
            const float p  = fminf(fmaxf(xc, EPS_), 1.0f - EPS_);
            const float q  = 1.0f - p;
            const float posT = 0.75f * q * q * (-LN2_ * flog2(p));
            const float negT = 0.25f * p * p * (-LN2_ * flog2(q));
            clsCorr = posT - negT;

            // regression loss: only components 0..3 (full box) survive the mask
            const float fx1 = s_ann[arg * 10 + 4];
            const float fy1 = s_ann[arg * 10 + 5];
            const float fx2 = s_ann[arg * 10 + 6];
            const float fy2 = s_ann[arg * 10 + 7];
            float gw = fx2 - fx1, gh = fy2 - fy1;
            const float gcx = fx1 + 0.5f * gw, gcy = fy1 + 0.5f * gh; // pre-clip centers
            gw = fmaxf(gw, 1.0f); gh = fmaxf(gh, 1.0f);
            const float t0 = ((gcx - acx) / aw) * 10.0f;
            const float t1 = ((gcy - acy) / ah) * 10.0f;
            const float t2 = (LN2_ * flog2(gw / aw)) * 5.0f;
            const float t3 = (LN2_ * flog2(gh / ah)) * 5.0f;
            const float4 r4 = ((const float4*)reg)[(size_t)(b * NA + a) * 2];
            const float d0 = fabsf(t0 - r4.x);
            const float d1 = fabsf(t1 - r4.y);
            const float d2 = fabsf(t2 - r4.z);
            const float d3 = fabsf(t3 - r4.w);
            const float beta = 1.0f / 9.0f;
            #define SL1(d) ((d) <= beta ? 4.5f * (d) * (d) : (d) - 0.5f / 9.0f)
            regLoss = SL1(d0) + SL1(d1) + SL1(d2) + SL1(d3);
            #undef SL1
        }
    }
    __syncthreads();

    // ---------------- Phase 2: streaming neg-term sweep, 5 batched loads/thread ----
    // block covers 1280 consecutive float4 = 64 anchors * 20
    const float4* base4 = (const float4*)(cls + (size_t)b * NA * NC) + (size_t)a0 * (NC / 4);

    float4 x[U];
    #pragma unroll
    for (int j = 0; j < U; ++j)
        x[j] = base4[j * BLOCK + tid];

    float clsSum = clsCorr;
    #pragma unroll
    for (int j = 0; j < U; ++j) {
        const int idx = j * BLOCK + tid;           // 0..1279
        const float C = s_coef[idx / (NC / 4)];
        const float4 x4 = x[j];

        float p0 = fminf(fmaxf(x4.x, EPS_), 1.0f - EPS_);
        float p1 = fminf(fmaxf(x4.y, EPS_), 1.0f - EPS_);
        float p2 = fminf(fmaxf(x4.z, EPS_), 1.0f - EPS_);
        float p3 = fminf(fmaxf(x4.w, EPS_), 1.0f - EPS_);

        float t0 = p0 * p0 * flog2(1.0f - p0);
        float t1 = p1 * p1 * flog2(1.0f - p1);
        float t2 = p2 * p2 * flog2(1.0f - p2);
        float t3 = p3 * p3 * flog2(1.0f - p3);

        clsSum = fmaf((t0 + t1) + (t2 + t3), C, clsSum);
    }

    // ---------------- Block reduce -> binned double atomics ------------------------
    const int wave = tid >> 6, lane = tid & 63;
    float rc = wave_reduce_f(clsSum);
    if (lane == 0) s_red[wave] = rc;
    if (wave == 0) {                       // regLoss/posCnt live only on wave 0
        float rr = wave_reduce_f(regLoss);
        float rp = wave_reduce_f(posCnt);
        if (lane == 0) { s_rp[0] = rr; s_rp[1] = rp; }
    }
    __syncthreads();
    if (tid == 0) {
        const float c = (s_red[0] + s_red[1]) + (s_red[2] + s_red[3]);
        const int bin = blockIdx.x & (BINS - 1);
        atomicAdd(&acc[(b * 3 + 0) * BINS + bin], (double)c);
        atomicAdd(&acc[(b * 3 + 1) * BINS + bin], (double)s_rp[0]);
        atomicAdd(&acc[(b * 3 + 2) * BINS + bin], (double)s_rp[1]);
    }
}

__global__ void focal_finalize(const double* __restrict__ acc, float* __restrict__ out) {
    __shared__ double g[NB * 3];
    const int tid  = threadIdx.x;          // 768 threads = 12 waves, one per (b,q)
    const int wave = tid >> 6, lane = tid & 63;
    double v = acc[wave * BINS + lane];
    v = wave_reduce_d(v);
    if (lane == 0) g[wave] = v;
    __syncthreads();
    if (tid == 0) {
        double clsTot = 0.0, regTot = 0.0;
        #pragma unroll
        for (int b = 0; b < NB; ++b) {
            const double np  = g[b * 3 + 2];
            const double npc = np < 1.0 ? 1.0 : np;
            clsTot += g[b * 3 + 0] / npc;
            regTot += (np > 0.0) ? g[b * 3 + 1] / (npc * 4.0) : 0.0;
        }
        out[0] = (float)(clsTot / NB);
        out[1] = (float)(regTot / NB);
    }
}

extern "C" void kernel_launch(void* const* d_in, const int* in_sizes, int n_in,
                              void* d_out, int out_size, void* d_ws, size_t ws_size,
                              hipStream_t stream) {
    const float* cls     = (const float*)d_in[0];   // (B, A, C)
    const float* reg     = (const float*)d_in[1];   // (B, A, 8)
    const float* anchors = (const float*)d_in[2];   // (1, A, 4)
    const float* ann     = (const float*)d_in[3];   // (B, M, 10)
    float* out = (float*)d_out;
    double* acc = (double*)d_ws;                    // NB*3*BINS doubles = 6 KB

    hipMemsetAsync(acc, 0, NB * 3 * BINS * sizeof(double), stream);

    dim3 grid(NA / APB, NB);                        // (1875, 4)
    focal_fused<<<grid, BLOCK, 0, stream>>>(cls, reg, anchors, ann, acc);
    focal_finalize<<<1, NB * 3 * BINS, 0, stream>>>(acc, out);
}